// Round 2
// baseline (420.065 us; speedup 1.0000x reference)
//
#include <hip/hip_runtime.h>

// Problem constants
#define NH 12
#define NTOK 196
#define TT 32
#define KW 4
#define NI 25088            // k*n*t tokens per batch element (= 98*256 exactly)
#define TSTRIDE 602112      // x flat stride for t+1 (same b,k)
#define NBLK 512            // co-resident by construction: 2 blocks/CU * 256 CU
#define NWAVES (NBLK * 4)
// x flat index: ((B*12 + h)*196 + n)*64 + c ;  B = (b*32 + t)*4 + k

// Cross-launch cumulative sync state (zero-init at module load; each launch
// adds exactly NBLK to g_counter1 and 4 to g_counter2, so iter = ticket/NBLK
// is launch-local and flags are monotone -> re-entrant without any reset).
__device__ int g_counter1;
__device__ int g_flag1;
__device__ int g_counter2;
__device__ int g_flag2;

__global__ __launch_bounds__(256, 2) void k_fused(
    const float* __restrict__ x, const float4* __restrict__ wf4,
    const float4* __restrict__ wb4,
    const float* __restrict__ fww, const float* __restrict__ fwb,
    const float* __restrict__ bww, const float* __restrict__ bwb,
    float* __restrict__ attn, float* __restrict__ winb,
    float* __restrict__ out)
{
  __shared__ float4 swf[192], swb[192];     // 6 KB pool weights
  __shared__ int   sidx[4096];              // 16 KB support indices
  __shared__ float swgt[4096];              // 16 KB support weights
  __shared__ float spool4[4][768];          // 12 KB per-wave pooled partials
  __shared__ float spool[768];              // 3 KB pooled vector
  __shared__ float part[2][88];
  __shared__ float praw[88];
  __shared__ float sred1[4], sred2[4];
  __shared__ float sbc;
  __shared__ int   scnt, sticket, ssetter;

  int tid = threadIdx.x;
  int wave = tid >> 6, lane = tid & 63;
  if (tid < 192) { swf[tid] = wf4[tid]; swb[tid] = wb4[tid]; }
  __syncthreads();

  // ---------------- phase A: attn logits (all blocks, grid-stride) ---------
  const float4* x4 = (const float4*)x;
  int gw = blockIdx.x * 4 + wave;
  int c4 = lane & 15, nq = lane >> 4;
  for (int tsk = gw; tsk < 256 * 49; tsk += NWAVES) {
    int B = tsk / 49, ngrp = tsk % 49;
    int n = ngrp * 4 + nq;                  // < 196 always
    float accf = 0.f, accb = 0.f;
    #pragma unroll
    for (int h = 0; h < NH; h++) {
      float4 xv = x4[((B * NH + h) * NTOK + n) * 16 + c4];
      float4 wf = swf[h * 16 + c4], wb = swb[h * 16 + c4];
      accf += xv.x * wf.x + xv.y * wf.y + xv.z * wf.z + xv.w * wf.w;
      accb += xv.x * wb.x + xv.y * wb.y + xv.z * wb.z + xv.w * wb.w;
    }
    #pragma unroll
    for (int m = 1; m < 16; m <<= 1) {
      accf += __shfl_xor(accf, m);
      accb += __shfl_xor(accb, m);
    }
    if ((lane & 15) == 0) {
      int b = B >> 7, t = (B >> 2) & 31, k = B & 3;
      int i = (k * NTOK + n) * TT + t;
      attn[b * NI + i] = accf;              // p = 0*2+b  (fwd)
      attn[(2 + b) * NI + i] = accb;        // p = 1*2+b  (bwd)
    }
  }
  __syncthreads();                          // drains this block's stores to L2
  if (tid == 0)
    sticket = __hip_atomic_fetch_add(&g_counter1, 1, __ATOMIC_ACQ_REL,
                                     __HIP_MEMORY_SCOPE_AGENT);
  __syncthreads();
  int ticket = sticket;
  int iter = ticket / NBLK, rank = ticket % NBLK;
  int target = iter + 1;

  // last arriver: all NBLK blocks' attn stores are published -> open flag1
  if (rank == NBLK - 1 && tid == 0)
    __hip_atomic_store(&g_flag1, target, __ATOMIC_RELEASE,
                       __HIP_MEMORY_SCOPE_AGENT);

  bool need_spin2 = true;

  if (rank >= NBLK - 4) {
    // ------------- phase B+C: entmax-1.5 + pool + win (4 blocks) ----------
    if (rank != NBLK - 1) {
      int spins = 0;
      while (__hip_atomic_load(&g_flag1, __ATOMIC_RELAXED,
                               __HIP_MEMORY_SCOPE_AGENT) < target) {
        __builtin_amdgcn_s_sleep(2);
        if (++spins > (1 << 20)) break;     // safety valve: fail visibly, not hang
      }
      (void)__hip_atomic_load(&g_flag1, __ATOMIC_ACQUIRE,
                              __HIP_MEMORY_SCOPE_AGENT);
    }
    int p = rank - (NBLK - 4);              // 0..3 = dir*2 + b
    int b = p & 1;
    const float* a = attn + p * NI;

    float v[98];
    float mx = -3.0e38f;
    #pragma unroll
    for (int r = 0; r < 98; r++) {
      v[r] = a[r * 256 + tid];
      mx = fmaxf(mx, v[r]);
    }
    #pragma unroll
    for (int m = 1; m < 64; m <<= 1) mx = fmaxf(mx, __shfl_xor(mx, m));
    if (lane == 0) sred1[wave] = mx;
    __syncthreads();
    if (tid == 0)
      sbc = fmaxf(fmaxf(sred1[0], sred1[1]), fmaxf(sred1[2], sred1[3]));
    __syncthreads();
    float amax = sbc;
    #pragma unroll
    for (int r = 0; r < 98; r++) v[r] = 0.5f * (v[r] - amax);

    float tau = -1.0f;                      // Newton on g(tau)=sum max(0,v-tau)^2-1
    for (int it = 0; it < 8; it++) {
      float s2 = 0.f, s1 = 0.f;
      #pragma unroll
      for (int r = 0; r < 98; r++) {
        float d = fmaxf(v[r] - tau, 0.f);
        s2 += d * d;
        s1 += d;
      }
      #pragma unroll
      for (int m = 1; m < 64; m <<= 1) {
        s2 += __shfl_xor(s2, m);
        s1 += __shfl_xor(s1, m);
      }
      if (lane == 0) { sred2[wave] = s2; sred1[wave] = s1; }
      __syncthreads();
      if (tid == 0) {
        float S2 = sred2[0] + sred2[1] + sred2[2] + sred2[3];
        float S1 = sred1[0] + sred1[1] + sred1[2] + sred1[3];
        sbc = tau + (S2 - 1.f) / fmaxf(2.f * S1, 1e-12f);
      }
      __syncthreads();
      tau = sbc;
      __syncthreads();
    }

    // compact support into LDS (support ~ tens for this data; 4096 cap)
    if (tid == 0) scnt = 0;
    __syncthreads();
    #pragma unroll
    for (int r = 0; r < 98; r++) {
      float d = v[r] - tau;
      if (d > 0.f) {
        int slot = atomicAdd(&scnt, 1);
        if (slot < 4096) { sidx[slot] = r * 256 + tid; swgt[slot] = d * d; }
      }
    }
    __syncthreads();
    int count = min(scnt, 4096);

    // pooled gather: waves stripe over support; each wave covers all 768 comps
    float acc12[12];
    #pragma unroll
    for (int h = 0; h < 12; h++) acc12[h] = 0.f;
    for (int e = wave; e < count; e += 4) {
      int i = sidx[e];
      float w = swgt[e];
      int t = i & 31, r2 = i >> 5;
      int n = r2 % NTOK, k = r2 / NTOK;
      int B = (b * TT + t) * KW + k;
      const float* xb = x + (size_t)B * (NH * NTOK * 64) + n * 64 + lane;
      #pragma unroll
      for (int h = 0; h < 12; h++) acc12[h] += w * xb[h * (NTOK * 64)];
    }
    #pragma unroll
    for (int h = 0; h < 12; h++) spool4[wave][h * 64 + lane] = acc12[h];
    __syncthreads();
    #pragma unroll
    for (int q = 0; q < 3; q++) {
      int j = q * 256 + tid;
      spool[j] = spool4[0][j] + spool4[1][j] + spool4[2][j] + spool4[3][j];
    }
    __syncthreads();

    // win GEMV: 2 segs x 88 cols (ww pre-warmed into LLC by spinning blocks)
    if (tid < 176) {
      int rseg = tid / 88, col = tid % 88;
      const float* ww = (p >> 1) ? bww : fww;
      float accw = 0.f;
      #pragma unroll 8
      for (int j = 0; j < 384; j++) {
        int r = rseg * 384 + j;
        accw += spool[r] * ww[r * 88 + col];
      }
      part[rseg][col] = accw;
    }
    __syncthreads();
    if (tid < 88) {
      const float* wbv = (p >> 1) ? bwb : fwb;
      praw[tid] = wbv[tid] + part[0][tid] + part[1][tid];
    }
    __syncthreads();
    if (tid < 8) {
      int f = tid;
      float vv[11];
      float mmx = -3.0e38f;
      #pragma unroll
      for (int j = 0; j < 11; j++) { vv[j] = praw[j * 8 + f]; mmx = fmaxf(mmx, vv[j]); }
      #pragma unroll
      for (int j = 0; j < 11; j++) vv[j] = 0.5f * (vv[j] - mmx);
      float lo = -1.f, hi = 0.f;
      for (int it = 0; it < 30; it++) {
        float mid = 0.5f * (lo + hi), s = 0.f;
        #pragma unroll
        for (int j = 0; j < 11; j++) { float d = fmaxf(vv[j] - mid, 0.f); s += d * d; }
        if (s >= 1.f) lo = mid; else hi = mid;
      }
      float tw = 0.5f * (lo + hi);
      #pragma unroll
      for (int j = 0; j < 11; j++) {
        float d = fmaxf(vv[j] - tw, 0.f);
        winb[p * 88 + f * 11 + j] = d * d * 0.125f;   // fold mean over f
      }
    }
    __syncthreads();
    if (tid == 0) {
      int t2 = __hip_atomic_fetch_add(&g_counter2, 1, __ATOMIC_ACQ_REL,
                                      __HIP_MEMORY_SCOPE_AGENT);
      if ((t2 & 3) == 3) {                  // last of the 4 p-blocks
        __hip_atomic_store(&g_flag2, target, __ATOMIC_RELEASE,
                           __HIP_MEMORY_SCOPE_AGENT);
        ssetter = 1;
      } else ssetter = 0;
    }
    __syncthreads();
    need_spin2 = (ssetter == 0);
  } else {
    // idle blocks: prefetch win_w into LLC (overlaps p-blocks' entmax), spin
    int idx = rank * 256 + tid;
    if (idx < 768 * 88 / 4) {
      float4 t1 = ((const float4*)fww)[idx];
      float4 t2 = ((const float4*)bww)[idx];
      asm volatile("" :: "v"(t1.x), "v"(t2.x));
    }
  }

  if (need_spin2) {
    int spins = 0;
    while (__hip_atomic_load(&g_flag2, __ATOMIC_RELAXED,
                             __HIP_MEMORY_SCOPE_AGENT) < target) {
      __builtin_amdgcn_s_sleep(32);
      if (++spins > (1 << 20)) break;       // safety valve
    }
    (void)__hip_atomic_load(&g_flag2, __ATOMIC_ACQUIRE,
                            __HIP_MEMORY_SCOPE_AGENT);
  }

  // ---------------- phase D: shift + pass-through (all blocks) -------------
  for (int tsk = gw; tsk < 96 * NTOK; tsk += NWAVES) {
    int bkh = tsk / NTOK, n = tsk % NTOK;
    int b = bkh / 48, rem = bkh % 48;
    int k = rem / 12, h = rem % 12;
    int f = lane & 7;
    float wjf[11], wjb[11];
    #pragma unroll
    for (int j = 0; j < 11; j++) {
      wjf[j] = winb[b * 88 + f * 11 + j];
      wjb[j] = winb[(2 + b) * 88 + f * 11 + j];
    }
    int base = ((b * 128 + k) * NH + h) * 12544 + n * 64 + lane;  // c == lane
    float xr[32];
    #pragma unroll
    for (int tp = 0; tp < 32; tp++) xr[tp] = x[base + tp * TSTRIDE];

    int src = (lane & 7) << 3;
    float val[32];
    float acc[32];

    // fwd: t_out = tp + 20 - j, valid tp in [0,21]
    #pragma unroll
    for (int t = 0; t < 32; t++) acc[t] = 0.f;
    #pragma unroll
    for (int tp = 0; tp <= 21; tp++) {
      #pragma unroll
      for (int j = 0; j < 11; j++) {
        int to = tp + 20 - j;
        if (to >= 0 && to < 32) acc[to] += wjf[j] * xr[tp];
      }
    }
    #pragma unroll
    for (int t = 0; t < 32; t++) {
      float s = acc[t];
      s += __shfl_xor(s, 1);
      s += __shfl_xor(s, 2);
      s += __shfl_xor(s, 4);
      float sf = __shfl(s, src);
      val[t] = (lane < 8) ? sf : xr[t];     // lanes 8..15 patched below
    }

    // bwd: t_out = tp - 10 - j, valid tp in [10,31]
    #pragma unroll
    for (int t = 0; t < 32; t++) acc[t] = 0.f;
    #pragma unroll
    for (int tp = 10; tp < 32; tp++) {
      #pragma unroll
      for (int j = 0; j < 11; j++) {
        int to = tp - 10 - j;
        if (to >= 0 && to < 32) acc[to] += wjb[j] * xr[tp];
      }
    }
    #pragma unroll
    for (int t = 0; t < 32; t++) {
      float s = acc[t];
      s += __shfl_xor(s, 1);
      s += __shfl_xor(s, 2);
      s += __shfl_xor(s, 4);
      float sb = __shfl(s, src);
      if (lane >= 8 && lane < 16) val[t] = sb;
      __builtin_nontemporal_store(val[t], &out[base + t * TSTRIDE]);
    }
  }
}

// ---------------------------------------------------------------------------
extern "C" void kernel_launch(void* const* d_in, const int* in_sizes, int n_in,
                              void* d_out, int out_size, void* d_ws, size_t ws_size,
                              hipStream_t stream)
{
  (void)in_sizes; (void)n_in; (void)out_size; (void)ws_size;
  const float* x   = (const float*)d_in[0];
  const float* fpw = (const float*)d_in[3];   // fwd_pool_w [768]
  const float* bpw = (const float*)d_in[5];   // bwd_pool_w [768]
  const float* fww = (const float*)d_in[7];   // fwd_win_w  [768*88]
  const float* fwb = (const float*)d_in[8];   // fwd_win_b  [88]
  const float* bww = (const float*)d_in[9];   // bwd_win_w  [768*88]
  const float* bwb = (const float*)d_in[10];  // bwd_win_b  [88]
  float* out = (float*)d_out;

  // workspace layout (floats): [attn(4*NI) | win(352)] — no memset needed
  float* W    = (float*)d_ws;
  float* attn = W;
  float* winb = attn + 4 * NI;

  k_fused<<<NBLK, 256, 0, stream>>>(x, (const float4*)fpw, (const float4*)bpw,
                                    fww, fwb, bww, bwb, attn, winb, out);
}

// Round 3
// 352.195 us; speedup vs baseline: 1.1927x; 1.1927x over previous
//
#include <hip/hip_runtime.h>

// Problem constants
#define NH 12
#define NTOK 196
#define TT 32
#define KW 4
#define NI 25088            // k*n*t tokens per batch element
#define TSTRIDE 602112      // x flat stride for t+1 (same b,k)
#define NBLKA 256           // K_A grid: 256 blocks x 1024 threads
#define NWAVESA (NBLKA * 16)
// x flat index: ((B*12 + h)*196 + n)*64 + c ;  B = (b*32 + t)*4 + k

// Cumulative ticket counter (zero-init at module load). Each launch adds
// exactly NBLKA, so rank = ticket % NBLKA is launch-local and the flag
// target iter+1 is monotone -> re-entrant across graph replays, no reset.
__device__ int g_counter1;
__device__ int g_flag1;

// ---------------------------------------------------------------------------
// K_A: attn logits (all blocks, grid-stride) -> ticket -> last 4 arrivers do
// entmax-1.5 + sparse pool + win GEMV + win entmax. Everyone else exits.
// Kernel completion is the sync for K_B (no second barrier needed).
__global__ __launch_bounds__(1024) void k_attn_pool(
    const float* __restrict__ x, const float4* __restrict__ wf4,
    const float4* __restrict__ wb4,
    const float* __restrict__ fww, const float* __restrict__ fwb,
    const float* __restrict__ bww, const float* __restrict__ bwb,
    float* __restrict__ attn, float* __restrict__ winb)
{
  __shared__ float4 swf[192], swb[192];     // 6 KB pool weights
  int tid = threadIdx.x;
  int wave = tid >> 6, lane = tid & 63;
  if (tid < 192) { swf[tid] = wf4[tid]; swb[tid] = wb4[tid]; }
  __syncthreads();

  // ---------------- phase A: attn logits ----------------------------------
  const float4* x4 = (const float4*)x;
  int gw = blockIdx.x * 16 + wave;
  int c4 = lane & 15, nq = lane >> 4;
  for (int tsk = gw; tsk < 256 * 49; tsk += NWAVESA) {
    int B = tsk / 49, ngrp = tsk % 49;
    int n = ngrp * 4 + nq;                  // < 196 always (49*4 = 196)
    float accf = 0.f, accb = 0.f;
    #pragma unroll
    for (int h = 0; h < NH; h++) {
      float4 xv = x4[((B * NH + h) * NTOK + n) * 16 + c4];
      float4 wf = swf[h * 16 + c4], wb = swb[h * 16 + c4];
      accf += xv.x * wf.x + xv.y * wf.y + xv.z * wf.z + xv.w * wf.w;
      accb += xv.x * wb.x + xv.y * wb.y + xv.z * wb.z + xv.w * wb.w;
    }
    #pragma unroll
    for (int m = 1; m < 16; m <<= 1) {
      accf += __shfl_xor(accf, m);
      accb += __shfl_xor(accb, m);
    }
    if ((lane & 15) == 0) {
      int b = B >> 7, t = (B >> 2) & 31, k = B & 3;
      int i = (k * NTOK + n) * TT + t;
      attn[b * NI + i] = accf;              // p = 0*2+b  (fwd)
      attn[(2 + b) * NI + i] = accb;        // p = 1*2+b  (bwd)
    }
  }
  __syncthreads();                          // all lanes' stores issued

  __shared__ int sticket;
  if (tid == 0)
    sticket = __hip_atomic_fetch_add(&g_counter1, 1, __ATOMIC_ACQ_REL,
                                     __HIP_MEMORY_SCOPE_AGENT);
  __syncthreads();
  int ticket = sticket;
  int rank = ticket % NBLKA;
  int target = ticket / NBLKA + 1;

  if (rank < NBLKA - 4) return;             // non-workers exit; no spinning

  // ---------------- phase B: entmax-1.5 + pool + win (4 worker blocks) ----
  int p = rank - (NBLKA - 4);               // 0..3 = dir*2 + b
  int b = p & 1;
  const float* ww = (p >> 1) ? bww : fww;
  const float* wbv = (p >> 1) ? bwb : fwb;

  if (rank == NBLKA - 1 && tid == 0)        // last arriver: publish attn
    __hip_atomic_store(&g_flag1, target, __ATOMIC_RELEASE,
                       __HIP_MEMORY_SCOPE_AGENT);

  // prefetch this worker's 270 KB win matrix into cache (overlaps the wait)
  {
    float dummy = 0.f;
    const float4* ww4 = (const float4*)ww;
    for (int q = tid; q < 768 * 88 / 4; q += 1024) {
      float4 tv = ww4[q];
      dummy += tv.x + tv.y + tv.z + tv.w;
    }
    asm volatile("" :: "v"(dummy));
  }

  if (rank != NBLKA - 1) {
    int spins = 0;
    while (__hip_atomic_load(&g_flag1, __ATOMIC_RELAXED,
                             __HIP_MEMORY_SCOPE_AGENT) < target) {
      __builtin_amdgcn_s_sleep(2);
      if (++spins > (1 << 20)) break;       // fail visibly, never hang
    }
    (void)__hip_atomic_load(&g_flag1, __ATOMIC_ACQUIRE,
                            __HIP_MEMORY_SCOPE_AGENT);
  }

  const float* a = attn + p * NI;
  float v[25];
  float mx = -3.0e38f;
  #pragma unroll
  for (int r = 0; r < 25; r++) {
    int i = r * 1024 + tid;
    v[r] = (i < NI) ? a[i] : -3.0e38f;
    mx = fmaxf(mx, v[r]);
  }
  __shared__ float sred1[16];
  __shared__ float sred2[16];
  __shared__ float sbc;
  int wv = tid >> 6;
  #pragma unroll
  for (int m = 1; m < 64; m <<= 1) mx = fmaxf(mx, __shfl_xor(mx, m));
  if ((tid & 63) == 0) sred1[wv] = mx;
  __syncthreads();
  if (tid == 0) {
    float m2 = sred1[0];
    for (int i2 = 1; i2 < 16; i2++) m2 = fmaxf(m2, sred1[i2]);
    sbc = m2;
  }
  __syncthreads();
  float amax = sbc;
  #pragma unroll
  for (int r = 0; r < 25; r++) v[r] = 0.5f * (v[r] - amax);

  float tau = -1.0f;        // Newton on g(tau) = sum max(0,v-tau)^2 - 1
  for (int it = 0; it < 8; it++) {
    float s2 = 0.f, s1 = 0.f;
    #pragma unroll
    for (int r = 0; r < 25; r++) {
      float d = fmaxf(v[r] - tau, 0.f);
      s2 += d * d;
      s1 += d;
    }
    #pragma unroll
    for (int m = 1; m < 64; m <<= 1) {
      s2 += __shfl_xor(s2, m);
      s1 += __shfl_xor(s1, m);
    }
    if ((tid & 63) == 0) { sred2[wv] = s2; sred1[wv] = s1; }
    __syncthreads();
    if (tid == 0) {
      float S2 = 0.f, S1 = 0.f;
      for (int i2 = 0; i2 < 16; i2++) { S2 += sred2[i2]; S1 += sred1[i2]; }
      sbc = tau + (S2 - 1.f) / fmaxf(2.f * S1, 1e-12f);
    }
    __syncthreads();
    tau = sbc;
    __syncthreads();
  }

  // compact support into LDS
  __shared__ int scnt;
  __shared__ int sidx[8192];
  __shared__ float swgt[8192];
  if (tid == 0) scnt = 0;
  __syncthreads();
  #pragma unroll
  for (int r = 0; r < 25; r++) {
    float d = v[r] - tau;
    if (d > 0.f) {
      int slot = atomicAdd(&scnt, 1);
      if (slot < 8192) { sidx[slot] = r * 1024 + tid; swgt[slot] = d * d; }
    }
  }
  __syncthreads();
  int count = min(scnt, 8192);

  // pooled gather: thread tid<768 owns component (h,c)
  __shared__ float spool[768];
  if (tid < 768) {
    int h = tid >> 6, c = tid & 63;
    float acc = 0.f;
    for (int e = 0; e < count; e++) {
      int i = sidx[e];
      float w = swgt[e];
      int t = i & 31, r2 = i >> 5;
      int n = r2 % NTOK, k = r2 / NTOK;
      int B = (b * TT + t) * KW + k;
      acc += w * x[((B * NH + h) * NTOK + n) * 64 + c];
    }
    spool[tid] = acc;
  }
  __syncthreads();

  // win GEMV: 8 segs x 88 cols (weights prefetched above)
  __shared__ float part[8][88];
  __shared__ float praw[88];
  if (tid < 704) {
    int rseg = tid / 88, col = tid % 88;
    float accw = 0.f;
    #pragma unroll 8
    for (int j = 0; j < 96; j++) {
      int r = rseg * 96 + j;
      accw += spool[r] * ww[r * 88 + col];
    }
    part[rseg][col] = accw;
  }
  __syncthreads();
  if (tid < 88) {
    float s = wbv[tid];
    #pragma unroll
    for (int g = 0; g < 8; g++) s += part[g][tid];
    praw[tid] = s;
  }
  __syncthreads();
  if (tid < 8) {
    int f = tid;
    float vv[11];
    float mmx = -3.0e38f;
    #pragma unroll
    for (int j = 0; j < 11; j++) { vv[j] = praw[j * 8 + f]; mmx = fmaxf(mmx, vv[j]); }
    #pragma unroll
    for (int j = 0; j < 11; j++) vv[j] = 0.5f * (vv[j] - mmx);
    float lo = -1.f, hi = 0.f;
    for (int it = 0; it < 30; it++) {
      float mid = 0.5f * (lo + hi), s = 0.f;
      #pragma unroll
      for (int j = 0; j < 11; j++) { float d = fmaxf(vv[j] - mid, 0.f); s += d * d; }
      if (s >= 1.f) lo = mid; else hi = mid;
    }
    float tw = 0.5f * (lo + hi);
    #pragma unroll
    for (int j = 0; j < 11; j++) {
      float d = fmaxf(vv[j] - tw, 0.f);
      winb[p * 88 + f * 11 + j] = d * d * 0.125f;   // fold mean over f
    }
  }
}

// ---------------------------------------------------------------------------
// K_B: shifted channels 0..15 AND pass-through 16..63 fused; x[t] read once
// into registers; f-reduce via xor butterfly; dense 256 B stores per (wave,t).
__global__ __launch_bounds__(256) void k_shift(
    const float* __restrict__ x, const float* __restrict__ win,
    float* __restrict__ out)
{
  int bkh = blockIdx.y;               // 96 = b*48 + k*12 + h
  int b = bkh / 48, rem = bkh % 48;
  int k = rem / 12, h = rem % 12;
  int wave = threadIdx.x >> 6, lane = threadIdx.x & 63;
  int n = blockIdx.x * 4 + wave;      // grid.x = 49, 49*4 = 196 exact
  int f = lane & 7;
  float wjf[11], wjb[11];
  #pragma unroll
  for (int j = 0; j < 11; j++) {
    wjf[j] = win[b * 88 + f * 11 + j];
    wjb[j] = win[(2 + b) * 88 + f * 11 + j];
  }
  int base = ((b * 128 + k) * NH + h) * 12544 + n * 64 + lane;  // c == lane
  float xr[32];
  #pragma unroll
  for (int tp = 0; tp < 32; tp++) xr[tp] = x[base + tp * TSTRIDE];

  int src = (lane & 7) << 3;
  float val[32];
  float acc[32];

  // fwd: t_out = tp + 20 - j, valid tp in [0,21]
  #pragma unroll
  for (int t = 0; t < 32; t++) acc[t] = 0.f;
  #pragma unroll
  for (int tp = 0; tp <= 21; tp++) {
    #pragma unroll
    for (int j = 0; j < 11; j++) {
      int to = tp + 20 - j;
      if (to >= 0 && to < 32) acc[to] += wjf[j] * xr[tp];
    }
  }
  #pragma unroll
  for (int t = 0; t < 32; t++) {
    float s = acc[t];
    s += __shfl_xor(s, 1);
    s += __shfl_xor(s, 2);
    s += __shfl_xor(s, 4);
    float sf = __shfl(s, src);
    val[t] = (lane < 8) ? sf : xr[t];     // lanes 8..15 patched below
  }

  // bwd: t_out = tp - 10 - j, valid tp in [10,31]
  #pragma unroll
  for (int t = 0; t < 32; t++) acc[t] = 0.f;
  #pragma unroll
  for (int tp = 10; tp < 32; tp++) {
    #pragma unroll
    for (int j = 0; j < 11; j++) {
      int to = tp - 10 - j;
      if (to >= 0 && to < 32) acc[to] += wjb[j] * xr[tp];
    }
  }
  #pragma unroll
  for (int t = 0; t < 32; t++) {
    float s = acc[t];
    s += __shfl_xor(s, 1);
    s += __shfl_xor(s, 2);
    s += __shfl_xor(s, 4);
    float sb = __shfl(s, src);
    if (lane >= 8 && lane < 16) val[t] = sb;
    __builtin_nontemporal_store(val[t], &out[base + t * TSTRIDE]);
  }
}

// ---------------------------------------------------------------------------
extern "C" void kernel_launch(void* const* d_in, const int* in_sizes, int n_in,
                              void* d_out, int out_size, void* d_ws, size_t ws_size,
                              hipStream_t stream)
{
  (void)in_sizes; (void)n_in; (void)out_size; (void)ws_size;
  const float* x   = (const float*)d_in[0];
  const float* fpw = (const float*)d_in[3];   // fwd_pool_w [768]
  const float* bpw = (const float*)d_in[5];   // bwd_pool_w [768]
  const float* fww = (const float*)d_in[7];   // fwd_win_w  [768*88]
  const float* fwb = (const float*)d_in[8];   // fwd_win_b  [88]
  const float* bww = (const float*)d_in[9];   // bwd_win_w  [768*88]
  const float* bwb = (const float*)d_in[10];  // bwd_win_b  [88]
  float* out = (float*)d_out;

  // workspace layout (floats): [attn(4*NI) | win(352)] — no memset needed
  float* W    = (float*)d_ws;
  float* attn = W;
  float* winb = attn + 4 * NI;

  k_attn_pool<<<NBLKA, 1024, 0, stream>>>(x, (const float4*)fpw,
                                          (const float4*)bpw, fww, fwb,
                                          bww, bwb, attn, winb);
  dim3 g5(49, 96);
  k_shift<<<g5, 256, 0, stream>>>(x, winb, out);
}

// Round 5
// 350.137 us; speedup vs baseline: 1.1997x; 1.0059x over previous
//
#include <hip/hip_runtime.h>

// Problem constants
#define NH 12
#define NTOK 196
#define TT 32
#define KW 4
#define NI 25088            // k*n*t tokens per batch element
#define TSTRIDE 602112      // x flat stride for t+1 (same b,k)
#define NBLKA 256           // K_A grid: 256 blocks x 1024 threads
#define NWAVESA (NBLKA * 16)
// x flat index: ((B*12 + h)*196 + n)*64 + c ;  B = (b*32 + t)*4 + k

// Cumulative ticket counter (zero-init at module load). Each launch adds
// exactly NBLKA, so rank = ticket % NBLKA is launch-local and the flag
// target iter+1 is monotone -> re-entrant across graph replays, no reset.
__device__ int g_counter1;
__device__ int g_flag1;

// ---------------------------------------------------------------------------
// K_A: attn logits (all blocks, grid-stride) -> ticket -> last 4 arrivers do
// entmax-1.5 + sparse pool + win GEMV + win entmax. Everyone else exits.
// Worker tail: 1-barrier/iter Newton (redundant per-thread tau update from
// LDS partials, double-buffered) + 16-wave pool gather into 8 LDS partials
// (two-step combine keeps static LDS ~68 KB, under the 78 KB proven in r3).
__global__ __launch_bounds__(1024) void k_attn_pool(
    const float* __restrict__ x, const float4* __restrict__ wf4,
    const float4* __restrict__ wb4,
    const float* __restrict__ fww, const float* __restrict__ fwb,
    const float* __restrict__ bww, const float* __restrict__ bwb,
    float* __restrict__ attn, float* __restrict__ winb)
{
  __shared__ float4 swf[192], swb[192];     // 6 KB pool weights
  int tid = threadIdx.x;
  int wave = tid >> 6, lane = tid & 63;
  if (tid < 192) { swf[tid] = wf4[tid]; swb[tid] = wb4[tid]; }
  __syncthreads();

  // ---------------- phase A: attn logits ----------------------------------
  const float4* x4 = (const float4*)x;
  int gw = blockIdx.x * 16 + wave;
  int c4 = lane & 15, nq = lane >> 4;
  for (int tsk = gw; tsk < 256 * 49; tsk += NWAVESA) {
    int B = tsk / 49, ngrp = tsk % 49;
    int n = ngrp * 4 + nq;                  // < 196 always (49*4 = 196)
    float accf = 0.f, accb = 0.f;
    #pragma unroll
    for (int h = 0; h < NH; h++) {
      float4 xv = x4[((B * NH + h) * NTOK + n) * 16 + c4];
      float4 wf = swf[h * 16 + c4], wb = swb[h * 16 + c4];
      accf += xv.x * wf.x + xv.y * wf.y + xv.z * wf.z + xv.w * wf.w;
      accb += xv.x * wb.x + xv.y * wb.y + xv.z * wb.z + xv.w * wb.w;
    }
    #pragma unroll
    for (int m = 1; m < 16; m <<= 1) {
      accf += __shfl_xor(accf, m);
      accb += __shfl_xor(accb, m);
    }
    if ((lane & 15) == 0) {
      int b = B >> 7, t = (B >> 2) & 31, k = B & 3;
      int i = (k * NTOK + n) * TT + t;
      attn[b * NI + i] = accf;              // p = 0*2+b  (fwd)
      attn[(2 + b) * NI + i] = accb;        // p = 1*2+b  (bwd)
    }
  }
  __syncthreads();                          // all lanes' stores issued

  __shared__ int sticket;
  if (tid == 0)
    sticket = __hip_atomic_fetch_add(&g_counter1, 1, __ATOMIC_ACQ_REL,
                                     __HIP_MEMORY_SCOPE_AGENT);
  __syncthreads();
  int ticket = sticket;
  int rank = ticket % NBLKA;
  int target = ticket / NBLKA + 1;

  if (rank < NBLKA - 4) return;             // non-workers exit; no spinning

  // ---------------- phase B: entmax-1.5 + pool + win (4 worker blocks) ----
  int p = rank - (NBLKA - 4);               // 0..3 = dir*2 + b
  int b = p & 1;
  const float* ww = (p >> 1) ? bww : fww;
  const float* wbv = (p >> 1) ? bwb : fwb;

  if (rank == NBLKA - 1 && tid == 0)        // last arriver: publish attn
    __hip_atomic_store(&g_flag1, target, __ATOMIC_RELEASE,
                       __HIP_MEMORY_SCOPE_AGENT);

  // prefetch this worker's 270 KB win matrix into cache (overlaps the wait)
  {
    float dummy = 0.f;
    const float4* ww4 = (const float4*)ww;
    for (int q = tid; q < 768 * 88 / 4; q += 1024) {
      float4 tv = ww4[q];
      dummy += tv.x + tv.y + tv.z + tv.w;
    }
    asm volatile("" :: "v"(dummy));
  }

  if (rank != NBLKA - 1) {
    int spins = 0;
    while (__hip_atomic_load(&g_flag1, __ATOMIC_RELAXED,
                             __HIP_MEMORY_SCOPE_AGENT) < target) {
      __builtin_amdgcn_s_sleep(2);
      if (++spins > (1 << 20)) break;       // fail visibly, never hang
    }
    (void)__hip_atomic_load(&g_flag1, __ATOMIC_ACQUIRE,
                            __HIP_MEMORY_SCOPE_AGENT);
  }

  const float* a = attn + p * NI;
  float v[25];
  float mx = -3.0e38f;
  #pragma unroll
  for (int r = 0; r < 25; r++) {
    int i = r * 1024 + tid;
    v[r] = (i < NI) ? a[i] : -3.0e38f;
    mx = fmaxf(mx, v[r]);
  }

  __shared__ float sM[16];
  __shared__ float sA[2][16], sB[2][16];    // double-buffered Newton partials
  #pragma unroll
  for (int m = 1; m < 64; m <<= 1) mx = fmaxf(mx, __shfl_xor(mx, m));
  if (lane == 0) sM[wave] = mx;
  __syncthreads();
  float amax = sM[0];
  #pragma unroll
  for (int i2 = 1; i2 < 16; i2++) amax = fmaxf(amax, sM[i2]);
  #pragma unroll
  for (int r = 0; r < 25; r++) v[r] = 0.5f * (v[r] - amax);

  // Newton on g(tau) = sum max(0,v-tau)^2 - 1 ; tau identical on all threads
  float tau = -1.0f;
  for (int it = 0; it < 8; it++) {
    int buf = it & 1;
    float s2 = 0.f, s1 = 0.f;
    #pragma unroll
    for (int r = 0; r < 25; r++) {
      float d = fmaxf(v[r] - tau, 0.f);
      s2 += d * d;
      s1 += d;
    }
    #pragma unroll
    for (int m = 1; m < 64; m <<= 1) {
      s2 += __shfl_xor(s2, m);
      s1 += __shfl_xor(s1, m);
    }
    if (lane == 0) { sA[buf][wave] = s2; sB[buf][wave] = s1; }
    __syncthreads();                        // one barrier per iteration
    float S2 = 0.f, S1 = 0.f;
    #pragma unroll
    for (int i2 = 0; i2 < 16; i2++) { S2 += sA[buf][i2]; S1 += sB[buf][i2]; }
    tau = tau + (S2 - 1.f) / fmaxf(2.f * S1, 1e-12f);
  }

  // compact support into LDS (support ~ hundreds; 4096 cap = 8x headroom)
  __shared__ int scnt;
  __shared__ int sidx[4096];
  __shared__ float swgt[4096];
  if (tid == 0) scnt = 0;
  __syncthreads();
  #pragma unroll
  for (int r = 0; r < 25; r++) {
    float d = v[r] - tau;
    if (d > 0.f) {
      int slot = atomicAdd(&scnt, 1);
      if (slot < 4096) { sidx[slot] = r * 1024 + tid; swgt[slot] = d * d; }
    }
  }
  __syncthreads();
  int count = min(scnt, 4096);

  // pooled gather, 16-wave parallel: wave w takes e = w, w+16, ...
  // lane owns channel c; 12 independent h-loads per element for ILP.
  // Combine into 8 LDS partial rows in two steps (no races, 24 KB not 48).
  __shared__ float spool8[8][768];
  __shared__ float spool[768];
  float acc12[12];
  #pragma unroll
  for (int h = 0; h < 12; h++) acc12[h] = 0.f;
  for (int e = wave; e < count; e += 16) {
    int i = sidx[e];
    float w = swgt[e];
    int t = i & 31, r2 = i >> 5;
    int n = r2 % NTOK, k = r2 / NTOK;
    int B = (b * TT + t) * KW + k;
    const float* xb = x + (size_t)B * (NH * NTOK * 64) + n * 64 + lane;
    #pragma unroll
    for (int h = 0; h < 12; h++) acc12[h] += w * xb[h * (NTOK * 64)];
  }
  if (wave >= 8) {
    #pragma unroll
    for (int h = 0; h < 12; h++) spool8[wave - 8][h * 64 + lane] = acc12[h];
  }
  __syncthreads();
  if (wave < 8) {
    #pragma unroll
    for (int h = 0; h < 12; h++) spool8[wave][h * 64 + lane] += acc12[h];
  }
  __syncthreads();
  if (tid < 768) {
    float s = 0.f;
    #pragma unroll
    for (int g = 0; g < 8; g++) s += spool8[g][tid];
    spool[tid] = s;
  }
  __syncthreads();

  // win GEMV: 8 segs x 88 cols (weights prefetched above)
  __shared__ float part[8][88];
  __shared__ float praw[88];
  if (tid < 704) {
    int rseg = tid / 88, col = tid % 88;
    float accw = 0.f;
    #pragma unroll 8
    for (int j = 0; j < 96; j++) {
      int r = rseg * 96 + j;
      accw += spool[r] * ww[r * 88 + col];
    }
    part[rseg][col] = accw;
  }
  __syncthreads();
  if (tid < 88) {
    float s = wbv[tid];
    #pragma unroll
    for (int g = 0; g < 8; g++) s += part[g][tid];
    praw[tid] = s;
  }
  __syncthreads();
  if (tid < 8) {
    int f = tid;
    float vv[11];
    float mmx = -3.0e38f;
    #pragma unroll
    for (int j = 0; j < 11; j++) { vv[j] = praw[j * 8 + f]; mmx = fmaxf(mmx, vv[j]); }
    #pragma unroll
    for (int j = 0; j < 11; j++) vv[j] = 0.5f * (vv[j] - mmx);
    float lo = -1.f, hi = 0.f;
    for (int it = 0; it < 30; it++) {
      float mid = 0.5f * (lo + hi), s = 0.f;
      #pragma unroll
      for (int j = 0; j < 11; j++) { float d = fmaxf(vv[j] - mid, 0.f); s += d * d; }
      if (s >= 1.f) lo = mid; else hi = mid;
    }
    float tw = 0.5f * (lo + hi);
    #pragma unroll
    for (int j = 0; j < 11; j++) {
      float d = fmaxf(vv[j] - tw, 0.f);
      winb[p * 88 + f * 11 + j] = d * d * 0.125f;   // fold mean over f
    }
  }
}

// ---------------------------------------------------------------------------
// K_B: shifted channels 0..15 AND pass-through 16..63 fused; x[t] read once
// into registers; f-reduce via xor butterfly; dense 256 B stores per (wave,t).
__global__ __launch_bounds__(256) void k_shift(
    const float* __restrict__ x, const float* __restrict__ win,
    float* __restrict__ out)
{
  int bkh = blockIdx.y;               // 96 = b*48 + k*12 + h
  int b = bkh / 48, rem = bkh % 48;
  int k = rem / 12, h = rem % 12;
  int wave = threadIdx.x >> 6, lane = threadIdx.x & 63;
  int n = blockIdx.x * 4 + wave;      // grid.x = 49, 49*4 = 196 exact
  int f = lane & 7;
  float wjf[11], wjb[11];
  #pragma unroll
  for (int j = 0; j < 11; j++) {
    wjf[j] = win[b * 88 + f * 11 + j];
    wjb[j] = win[(2 + b) * 88 + f * 11 + j];
  }
  int base = ((b * 128 + k) * NH + h) * 12544 + n * 64 + lane;  // c == lane
  float xr[32];
  #pragma unroll
  for (int tp = 0; tp < 32; tp++) xr[tp] = x[base + tp * TSTRIDE];

  int src = (lane & 7) << 3;
  float val[32];
  float acc[32];

  // fwd: t_out = tp + 20 - j, valid tp in [0,21]
  #pragma unroll
  for (int t = 0; t < 32; t++) acc[t] = 0.f;
  #pragma unroll
  for (int tp = 0; tp <= 21; tp++) {
    #pragma unroll
    for (int j = 0; j < 11; j++) {
      int to = tp + 20 - j;
      if (to >= 0 && to < 32) acc[to] += wjf[j] * xr[tp];
    }
  }
  #pragma unroll
  for (int t = 0; t < 32; t++) {
    float s = acc[t];
    s += __shfl_xor(s, 1);
    s += __shfl_xor(s, 2);
    s += __shfl_xor(s, 4);
    float sf = __shfl(s, src);
    val[t] = (lane < 8) ? sf : xr[t];     // lanes 8..15 patched below
  }

  // bwd: t_out = tp - 10 - j, valid tp in [10,31]
  #pragma unroll
  for (int t = 0; t < 32; t++) acc[t] = 0.f;
  #pragma unroll
  for (int tp = 10; tp < 32; tp++) {
    #pragma unroll
    for (int j = 0; j < 11; j++) {
      int to = tp - 10 - j;
      if (to >= 0 && to < 32) acc[to] += wjb[j] * xr[tp];
    }
  }
  #pragma unroll
  for (int t = 0; t < 32; t++) {
    float s = acc[t];
    s += __shfl_xor(s, 1);
    s += __shfl_xor(s, 2);
    s += __shfl_xor(s, 4);
    float sb = __shfl(s, src);
    if (lane >= 8 && lane < 16) val[t] = sb;
    __builtin_nontemporal_store(val[t], &out[base + t * TSTRIDE]);
  }
}

// ---------------------------------------------------------------------------
extern "C" void kernel_launch(void* const* d_in, const int* in_sizes, int n_in,
                              void* d_out, int out_size, void* d_ws, size_t ws_size,
                              hipStream_t stream)
{
  (void)in_sizes; (void)n_in; (void)out_size; (void)ws_size;
  const float* x   = (const float*)d_in[0];
  const float* fpw = (const float*)d_in[3];   // fwd_pool_w [768]
  const float* bpw = (const float*)d_in[5];   // bwd_pool_w [768]
  const float* fww = (const float*)d_in[7];   // fwd_win_w  [768*88]
  const float* fwb = (const float*)d_in[8];   // fwd_win_b  [88]
  const float* bww = (const float*)d_in[9];   // bwd_win_w  [768*88]
  const float* bwb = (const float*)d_in[10];  // bwd_win_b  [88]
  float* out = (float*)d_out;

  // workspace layout (floats): [attn(4*NI) | win(352)] — no memset needed
  float* W    = (float*)d_ws;
  float* attn = W;
  float* winb = attn + 4 * NI;

  k_attn_pool<<<NBLKA, 1024, 0, stream>>>(x, (const float4*)fpw,
                                          (const float4*)bpw, fww, fwb,
                                          bww, bwb, attn, winb);
  dim3 g5(49, 96);
  k_shift<<<g5, 256, 0, stream>>>(x, winb, out);
}